// Round 4
// baseline (173.974 us; speedup 1.0000x reference)
//
#include <hip/hip_runtime.h>

// PositionEncoding: out[b,s,:] = is_class ? E_class[class_ids[b,s],:]
//                                         : interleaved sin/cos(v * 2^i * pi)
// B=64, S=8192, CLASS_NUM=4096, LEVELS=32, E=64. Output fp32 128 MiB -> memory-bound
// floor ~20-25 us at the ~6.7 TB/s the harness fills demonstrate.
//
// Numerics (validated round 1, absmax 3.9e-3 vs threshold 8.9e-2):
// reference arg = fp32(v * 2^i * pi_f) = 2^i * w with w = fp32(v*pi_f) (pow2 scale
// exact). Track revolutions in double: uA = w * (2^(2j)/2pi); frac -> hardware
// v_sin_f32/v_cos_f32 (revolution input). Amplification error ~2e-7 rev.
//
// This round: one chunk (float4 = 2 levels) per thread, and the per-level scale
// 2^(2j)/(2pi) is built by adding j<<21 to the high word of the double constant
// 1/(2pi) = 0x3FC45F306DC9C883 (exponent bump by 2j) -- 1 int op instead of
// cvt+mul. frac via v_floor_f64 + sub (uA >= 0 always since v in [0,1)).

constexpr int CHUNKS = 64 * 8192 * 16;   // B*S rows x 16 float4 per row = 8.4M

__global__ __launch_bounds__(256, 8) void PositionEncoding_61856118997301_kernel(
    const float* __restrict__ values,
    const float* __restrict__ E_class,
    const int*   __restrict__ class_ids,
    const int*   __restrict__ is_class,
    float4*      __restrict__ out)
{
    const float PI_F = 3.14159274101257324f;   // fp32(pi), matches reference freqs

    int g   = blockIdx.x * 256 + threadIdx.x;  // one chunk per thread, exact grid
    int row = g >> 4;                          // which (b,s) element
    int j   = g & 15;                          // levels 2j, 2j+1

    float4 r;
    if (is_class[row] != 0) {
        // 16 consecutive lanes read 16 consecutive float4s of one E_class row
        r = reinterpret_cast<const float4*>(E_class)[(class_ids[row] << 4) + j];
    } else {
        float  w = values[row] * PI_F;                 // == ref arg / 2^i (exact pow2)
        // m = 2^(2j) / (2*pi): bump exponent of 1/(2pi) by 2j via bit surgery
        long long mbits = 0x3FC45F306DC9C883LL + ((long long)j << 53);
        double m  = __longlong_as_double(mbits);
        double uA = (double)w * m;                     // revolutions at level 2j
        double uB = uA + uA;                           // level 2j+1 (exact)
        float  fA = (float)(uA - floor(uA));           // frac, uA >= 0
        float  fB = (float)(uB - floor(uB));
        r.x = __builtin_amdgcn_sinf(fA);               // v_sin_f32: sin(2*pi*frac)
        r.y = __builtin_amdgcn_cosf(fA);
        r.z = __builtin_amdgcn_sinf(fB);
        r.w = __builtin_amdgcn_cosf(fB);
    }
    out[g] = r;   // wave store = 64 x 16B contiguous = 1 KB
}

extern "C" void kernel_launch(void* const* d_in, const int* in_sizes, int n_in,
                              void* d_out, int out_size, void* d_ws, size_t ws_size,
                              hipStream_t stream) {
    const float* values    = (const float*)d_in[0];
    const float* E_class   = (const float*)d_in[1];
    const int*   class_ids = (const int*)d_in[2];
    const int*   is_class  = (const int*)d_in[3];
    float4*      out       = (float4*)d_out;

    dim3 block(256);
    dim3 grid(CHUNKS / 256);   // 32768 blocks, one chunk per thread, no tail
    PositionEncoding_61856118997301_kernel<<<grid, block, 0, stream>>>(
        values, E_class, class_ids, is_class, out);
}